// Round 8
// baseline (89.386 us; speedup 1.0000x reference)
//
#include <hip/hip_runtime.h>
#include <math.h>

#define BB  8
#define HH  512
#define WW  512
#define HW  (HH*WW)

#define TSX 32           // tile width
#define TSY 32           // tile height
#define GR  34           // guidance tile (halo 1)
#define GSS 36           // g_sh row stride (u16)
#define GPLANE (GR*GSS)
#define FR  36           // flow tile (halo 2)
#define FPS 37           // f_lds row stride (f32)
#define FPLANE (FR*FPS)

#define WS_GOFF 32768    // G buffer offset in d_ws

typedef __attribute__((ext_vector_type(8))) short  short8;
typedef __attribute__((ext_vector_type(4))) short  short4v;
typedef __attribute__((ext_vector_type(4))) float  float4v;
typedef __attribute__((ext_vector_type(4))) int    int4v;
typedef __attribute__((ext_vector_type(4))) uint   uint4v;
typedef __attribute__((ext_vector_type(2))) float  float2v;

#define MFMA16x32(a,b,c) __builtin_amdgcn_mfma_f32_16x16x32_bf16((a),(b),(c),0,0,0)

#if __has_builtin(__builtin_amdgcn_mfma_f32_16x16x16bf16_1k)
  #define HAVE_1K 1
#endif

static __device__ __forceinline__ float4v mfma_k16(short4v a, short4v b, float4v c) {
#ifdef HAVE_1K
    return __builtin_amdgcn_mfma_f32_16x16x16bf16_1k(a, b, c, 0, 0, 0);
#else
    asm volatile("v_mfma_f32_16x16x16_bf16 %0, %1, %2, %0" : "+v"(c) : "v"(a), "v"(b));
    return c;
#endif
}
static __device__ __forceinline__ void mfma_pre_fence() {
#ifndef HAVE_1K
    asm volatile("s_nop 3");          // VALU->MFMA srcA/B hazard (asm path only)
#endif
}
static __device__ __forceinline__ void mfma_post_fence() {
#ifndef HAVE_1K
    asm volatile("s_nop 7\n\ts_nop 7"); // MFMA->VALU acc read hazard (asm path only)
#endif
}

// launder: make value opaque so the compiler cannot rematerialize its load
template <typename T>
static __device__ __forceinline__ void keep(T& x) { asm volatile("" : "+v"(x)); }

static __device__ __forceinline__ uint  fu(float f) { return __float_as_uint(f); }
static __device__ __forceinline__ float uf(uint u)  { return __uint_as_float(u); }

static __device__ __forceinline__ ushort f2bf_rne(float f) {
    uint u = fu(f);
    u += 0x7fffu + ((u >> 16) & 1u);
    return (ushort)(u >> 16);
}
static __device__ __forceinline__ void split_rne(float f, ushort& hi, ushort& lo) {
    hi = f2bf_rne(f);
    float r = f - uf((uint)hi << 16);
    lo = f2bf_rne(r);
}

// tap index for conv2 output row position (qr, rr) within a channel (row-permuted
// so combine offsets are compile-time per (mt, r)); -1 = dead row (zero weights)
static __device__ __forceinline__ int tap_kk(int mtodd, int qr, int rr) {
    if (!mtodd) return 5 * qr + rr;       // taps (qr, 0..4) minus last col
    if (rr == 0) return 5 * qr + 4;       // taps (qr, 4)
    if (rr == 1) return 20 + qr;          // taps (4, qr)
    if (rr == 2 && qr == 3) return 24;    // tap  (4, 4)
    return -1;
}

// ===================== setup (device fn, run by K1 block 0) =====================
// chunks (uint4 ws[chunk*64 + lane]):
//  0..1  a1h[t]  2..3 a1l[t]    conv1 A (16x16x32): row=16t+c, k=8q+i
//  4..7  a2h[mt] 8..11 a2l[mt]  conv2 A (16x16x16): row=c->tap, k=oc=16t+4q+i
//                               packed {t0:2xu32, t1:2xu32}
// 12..13 bi1[t]                 b1 at conv1 C rows
// 14..17 bi2[mt]                b2 at permuted conv2 C rows (or 0)
// 18..19 off1 int4 x2           guidance gather offsets (u16 units; pad->0)
static __device__ void setup_lane(const float* __restrict__ w1, const float* __restrict__ b1,
                                  const float* __restrict__ w2, const float* __restrict__ b2,
                                  uint4v* __restrict__ ws, int L)
{
    const int c = L & 15, q = L >> 4;

    #pragma unroll
    for (int t = 0; t < 2; ++t) {
        short8 hi8, lo8;
        #pragma unroll
        for (int i = 0; i < 8; ++i) {
            const int k = 8 * q + i;
            const float f = (k < 27) ? w1[(16 * t + c) * 27 + k] : 0.f;
            ushort h_, l_; split_rne(f, h_, l_);
            hi8[i] = (short)h_; lo8[i] = (short)l_;
        }
        *reinterpret_cast<short8*>(&ws[(0 + t) * 64 + L]) = hi8;
        *reinterpret_cast<short8*>(&ws[(2 + t) * 64 + L]) = lo8;
    }
    #pragma unroll
    for (int mt = 0; mt < 4; ++mt) {
        const int ch = mt >> 1;
        const int kk = tap_kk(mt & 1, c >> 2, c & 3);   // A row = c -> tap
        uint4v hi4, lo4;
        #pragma unroll
        for (int t = 0; t < 2; ++t) {
            ushort h[4], l[4];
            #pragma unroll
            for (int i = 0; i < 4; ++i) {
                const int oc = 16 * t + 4 * q + i;
                const float f = (kk >= 0) ? w2[(25 * ch + kk) * 32 + oc] : 0.f;
                split_rne(f, h[i], l[i]);
            }
            hi4[2 * t]     = (uint)h[0] | ((uint)h[1] << 16);
            hi4[2 * t + 1] = (uint)h[2] | ((uint)h[3] << 16);
            lo4[2 * t]     = (uint)l[0] | ((uint)l[1] << 16);
            lo4[2 * t + 1] = (uint)l[2] | ((uint)l[3] << 16);
        }
        ws[(4 + mt) * 64 + L] = hi4;
        ws[(8 + mt) * 64 + L] = lo4;
    }
    #pragma unroll
    for (int t = 0; t < 2; ++t) {
        float4v v;
        #pragma unroll
        for (int r = 0; r < 4; ++r) v[r] = b1[16 * t + 4 * q + r];
        *reinterpret_cast<float4v*>(&ws[(12 + t) * 64 + L]) = v;
    }
    #pragma unroll
    for (int mt = 0; mt < 4; ++mt) {
        const int ch = mt >> 1;
        float4v v;
        #pragma unroll
        for (int r = 0; r < 4; ++r) {
            const int kk = tap_kk(mt & 1, q, r);        // C row = 4q+r -> tap
            v[r] = (kk >= 0) ? b2[25 * ch + kk] : 0.f;
        }
        *reinterpret_cast<float4v*>(&ws[(14 + mt) * 64 + L]) = v;
    }
    #pragma unroll
    for (int hf = 0; hf < 2; ++hf) {
        int4v o;
        #pragma unroll
        for (int i2 = 0; i2 < 4; ++i2) {
            const int k = 8 * q + 4 * hf + i2;
            if (k < 27) {
                const int ic = k / 9, r9 = k - ic * 9;
                o[i2] = ic * GPLANE + (r9 / 3) * GSS + (r9 % 3);
            } else o[i2] = 0;   // garbage read ok: A weight column is zero
        }
        *reinterpret_cast<int4v*>(&ws[(18 + hf) * 64 + L]) = o;
    }
}

// ================== K1: guidance (2 px/thread) + folded setup ==================
__global__ __launch_bounds__(256)
void guidance_kernel(const float* __restrict__ v0,
                     const float* __restrict__ v2,
                     const float* __restrict__ w1, const float* __restrict__ b1,
                     const float* __restrict__ w2, const float* __restrict__ b2,
                     ushort* __restrict__ G, uint4v* __restrict__ ws)
{
    if (blockIdx.x == 0 && threadIdx.x < 64)
        setup_lane(w1, b1, w2, b2, ws, threadIdx.x);

    const int idx = (blockIdx.x * 256 + threadIdx.x) * 2;
    const int x = idx & (WW - 1);            // even
    const int y = (idx >> 9) & (HH - 1);
    const int b = idx >> 18;

    const float* v0b = v0 + (size_t)b * 2 * HW;
    const float* v2b = v2 + (size_t)b * 2 * HW;

    const float2v f0p = *reinterpret_cast<const float2v*>(v0b + y * WW + x);
    const float2v f1p = *reinterpret_cast<const float2v*>(v0b + HW + y * WW + x);

    ushort o0[2], o1[2], o2[2];
    #pragma unroll
    for (int j = 0; j < 2; ++j) {
        const int xj = x + j;
        const float f0 = f0p[j], f1 = f1p[j];
        const float sgx = (-1.0f + xj * (2.0f / (WW - 1))) + f0 * (2.0f / WW);
        const float sgy = (-1.0f + y  * (2.0f / (HH - 1))) + f1 * (2.0f / HH);
        const float ixf = (sgx + 1.0f) * (0.5f * (WW - 1));
        const float iyf = (sgy + 1.0f) * (0.5f * (HH - 1));
        const float x0f = floorf(ixf), y0f = floorf(iyf);
        const int   x0  = (int)x0f,   y0i = (int)y0f;
        const float wx1 = ixf - x0f, wx0 = 1.0f - wx1;
        const float wy1 = iyf - y0f, wy0 = 1.0f - wy1;
        float s0 = 0.f, s1 = 0.f;
        #pragma unroll
        for (int cy = 0; cy < 2; ++cy) {
            const int yy = y0i + cy;
            const float wy = cy ? wy1 : wy0;
            if (yy >= 0 && yy < HH) {
                #pragma unroll
                for (int cx = 0; cx < 2; ++cx) {
                    const int xx = x0 + cx;
                    if (xx >= 0 && xx < WW) {
                        const float wgt = wy * (cx ? wx1 : wx0);
                        const int i2 = yy * WW + xx;
                        s0 = fmaf(wgt, v2b[i2], s0);
                        s1 = fmaf(wgt, v2b[HW + i2], s1);
                    }
                }
            }
        }
        const float fb0 = f0 + s0;
        const float fb1 = f1 + s1;
        const float wv  = __expf(-sqrtf(fmaf(fb0, fb0, fb1 * fb1)));
        o0[j] = f2bf_rne(fb0); o1[j] = f2bf_rne(fb1); o2[j] = f2bf_rne(wv);
    }
    const size_t base = (size_t)b * 3 * HW + y * WW + x;
    *reinterpret_cast<uint*>(&G[base])          = (uint)o0[0] | ((uint)o0[1] << 16);
    *reinterpret_cast<uint*>(&G[base + HW])     = (uint)o1[0] | ((uint)o1[1] << 16);
    *reinterpret_cast<uint*>(&G[base + 2 * HW]) = (uint)o2[0] | ((uint)o2[1] << 16);
}

// =============== K2: convs + combine, 32x32 tile, no h-bounce ===============
__global__ __launch_bounds__(256, 3)
void refine_kernel(const float* __restrict__ v0,
                   const ushort* __restrict__ G,
                   const uint4v* __restrict__ P,
                   float* __restrict__ out)
{
    __shared__ ushort g_sh[3 * GPLANE];           // bf16 guidance tile
    __shared__ float  f_lds[2 * FPLANE];          // flow tile (halo 2)

    const int bx0 = blockIdx.x * TSX;
    const int by0 = blockIdx.y * TSY;
    const int b   = blockIdx.z;
    const int tid = threadIdx.x;
    const int w   = tid >> 6;
    const int L   = tid & 63;
    const int c   = L & 15;
    const int q   = L >> 4;

    const float*  v0b = v0 + (size_t)b * 2 * HW;
    const ushort* Gb  = G + (size_t)b * 3 * HW;

    // ---- per-lane params, loaded once and laundered (no remat) ----
    short8 a1h[2], a1l[2];
    #pragma unroll
    for (int t = 0; t < 2; ++t) {
        a1h[t] = *reinterpret_cast<const short8*>(&P[(0 + t) * 64 + L]); keep(a1h[t]);
        a1l[t] = *reinterpret_cast<const short8*>(&P[(2 + t) * 64 + L]); keep(a1l[t]);
    }
    short4v a2h[4][2], a2l[4][2];
    #pragma unroll
    for (int mt = 0; mt < 4; ++mt) {
        uint4v uh = P[(4 + mt) * 64 + L]; keep(uh);
        uint4v ul = P[(8 + mt) * 64 + L]; keep(ul);
        #pragma unroll
        for (int t = 0; t < 2; ++t) {
            short4v sh, sl;
            #pragma unroll
            for (int e = 0; e < 4; ++e) {
                sh[e] = (short)((uh[2 * t + (e >> 1)] >> (16 * (e & 1))) & 0xFFFFu);
                sl[e] = (short)((ul[2 * t + (e >> 1)] >> (16 * (e & 1))) & 0xFFFFu);
            }
            a2h[mt][t] = sh; a2l[mt][t] = sl;
        }
    }
    float4v bi1[2], bi2[4];
    #pragma unroll
    for (int t = 0; t < 2; ++t) {
        bi1[t] = *reinterpret_cast<const float4v*>(&P[(12 + t) * 64 + L]); keep(bi1[t]);
    }
    #pragma unroll
    for (int mt = 0; mt < 4; ++mt) {
        bi2[mt] = *reinterpret_cast<const float4v*>(&P[(14 + mt) * 64 + L]); keep(bi2[mt]);
    }
    int off1[8];
    #pragma unroll
    for (int hf = 0; hf < 2; ++hf) {
        int4v o = *reinterpret_cast<const int4v*>(&P[(18 + hf) * 64 + L]); keep(o);
        #pragma unroll
        for (int i2 = 0; i2 < 4; ++i2) off1[hf * 4 + i2] = o[i2];
    }

    // ---- stage flow tile (36x36, halo 2) ----
    for (int i = tid; i < FR * FR; i += 256) {
        const int ly = i / FR, lx = i - (i / FR) * FR;
        const int y = by0 - 2 + ly, x = bx0 - 2 + lx;
        float f0 = 0.f, f1 = 0.f;
        if ((unsigned)y < HH && (unsigned)x < WW) {
            f0 = v0b[y * WW + x];
            f1 = v0b[HW + y * WW + x];
        }
        f_lds[ly * FPS + lx]          = f0;
        f_lds[FPLANE + ly * FPS + lx] = f1;
    }
    // ---- stage guidance tile (34x34, halo 1), 3 bf16 planes ----
    for (int i = tid; i < GR * GR; i += 256) {
        const int ly = i / GR, lx = i - (i / GR) * GR;
        const int y = by0 - 1 + ly, x = bx0 - 1 + lx;
        ushort u0 = 0, u1 = 0, u2 = 0;
        if ((unsigned)y < HH && (unsigned)x < WW) {
            const size_t gi = (size_t)y * WW + x;
            u0 = Gb[gi];
            u1 = Gb[gi + HW];
            u2 = Gb[gi + 2 * HW];
        }
        g_sh[ly * GSS + lx]              = u0;
        g_sh[GPLANE + ly * GSS + lx]     = u1;
        g_sh[2 * GPLANE + ly * GSS + lx] = u2;
    }
    __syncthreads();

    // ---- 16 groups of 16 px per wave: rows 8w..8w+7, halves 0/1 ----
    for (int g = 0; g < 16; ++g) {
        const int py = 8 * w + (g >> 1);
        const int px = 16 * (g & 1) + c;
        const int gb = py * GSS + px;

        // B1 frag: 8 bf16 gathers
        short8 b1;
        #pragma unroll
        for (int i = 0; i < 8; ++i) b1[i] = (short)g_sh[off1[i] + gb];

        // conv3x3 GEMM (bf16 B, split A), bias in C
        float4v acc1_0 = bi1[0], acc1_1 = bi1[1];
        acc1_0 = MFMA16x32(a1l[0], b1, acc1_0);
        acc1_0 = MFMA16x32(a1h[0], b1, acc1_0);
        acc1_1 = MFMA16x32(a1l[1], b1, acc1_1);
        acc1_1 = MFMA16x32(a1h[1], b1, acc1_1);

        // ReLU + split hi/lo -> conv2 B frags DIRECTLY in registers:
        // conv1 C row (4q+r) == conv2 K=16 B slot (k=4q+i). No LDS bounce.
        short4v b2h[2], b2l[2];
        #pragma unroll
        for (int t = 0; t < 2; ++t) {
            const float4v a = t ? acc1_1 : acc1_0;
            #pragma unroll
            for (int r = 0; r < 4; ++r) {
                const float rv = fmaxf(a[r], 0.f);
                const uint  uv = fu(rv);
                const uint  mh = uv & 0xFFFF0000u;
                const float lv = rv - uf(mh);            // exact residual
                b2h[t][r] = (short)(uv >> 16);
                b2l[t][r] = (short)(fu(lv) >> 16);
            }
        }

        // conv1x1 GEMM via 16x16x16 (split 3-term, 2 k-tiles), bias in C
        float4v acc2[4] = {bi2[0], bi2[1], bi2[2], bi2[3]};
        mfma_pre_fence();
        #pragma unroll
        for (int mt = 0; mt < 4; ++mt) {
            acc2[mt] = mfma_k16(a2h[mt][0], b2h[0], acc2[mt]);
            acc2[mt] = mfma_k16(a2h[mt][0], b2l[0], acc2[mt]);
            acc2[mt] = mfma_k16(a2l[mt][0], b2h[0], acc2[mt]);
            acc2[mt] = mfma_k16(a2h[mt][1], b2h[1], acc2[mt]);
            acc2[mt] = mfma_k16(a2h[mt][1], b2l[1], acc2[mt]);
            acc2[mt] = mfma_k16(a2l[mt][1], b2h[1], acc2[mt]);
        }
        mfma_post_fence();

        // combine: compile-time tap offsets (row-permuted conv2 output)
        const int pyb   = py * FPS + px;
        const int base0 = pyb + q * FPS;          // taps (q, 0..4)
        const int b4    = pyb + 4 * FPS + q;      // tap  (4, q)
        const int base1 = base0 + FPLANE;
        const int b41   = b4 + FPLANE;

        float s0 = 0.f, s1 = 0.f;
        s0 = fmaf(acc2[0][0], f_lds[base0],      s0);
        s0 = fmaf(acc2[0][1], f_lds[base0 + 1],  s0);
        s0 = fmaf(acc2[0][2], f_lds[base0 + 2],  s0);
        s0 = fmaf(acc2[0][3], f_lds[base0 + 3],  s0);
        s0 = fmaf(acc2[1][0], f_lds[base0 + 4],  s0);
        s0 = fmaf(acc2[1][1], f_lds[b4],         s0);
        s0 = fmaf(acc2[1][2], f_lds[base0 + 41], s0);   // (4,4): kern==0 unless q==3
        s1 = fmaf(acc2[2][0], f_lds[base1],      s1);
        s1 = fmaf(acc2[2][1], f_lds[base1 + 1],  s1);
        s1 = fmaf(acc2[2][2], f_lds[base1 + 2],  s1);
        s1 = fmaf(acc2[2][3], f_lds[base1 + 3],  s1);
        s1 = fmaf(acc2[3][0], f_lds[base1 + 4],  s1);
        s1 = fmaf(acc2[3][1], f_lds[b41],        s1);
        s1 = fmaf(acc2[3][2], f_lds[base1 + 41], s1);

        s0 += __shfl_xor(s0, 16);
        s0 += __shfl_xor(s0, 32);
        s1 += __shfl_xor(s1, 16);
        s1 += __shfl_xor(s1, 32);

        if (q == 0) {
            const int y = by0 + py, x = bx0 + px;
            out[((size_t)b * 2 + 0) * HW + y * WW + x] = s0;
            out[((size_t)b * 2 + 1) * HW + y * WW + x] = s1;
        }
    }
}

extern "C" void kernel_launch(void* const* d_in, const int* in_sizes, int n_in,
                              void* d_out, int out_size, void* d_ws, size_t ws_size,
                              hipStream_t stream) {
    const float* v0 = (const float*)d_in[0];
    const float* v2 = (const float*)d_in[1];
    const float* w1 = (const float*)d_in[2];
    const float* b1 = (const float*)d_in[3];
    const float* w2 = (const float*)d_in[4];
    const float* b2 = (const float*)d_in[5];
    uint4v* ws = (uint4v*)d_ws;
    ushort* G  = (ushort*)((char*)d_ws + WS_GOFF);

    guidance_kernel<<<(BB * HW) / 512, 256, 0, stream>>>(v0, v2, w1, b1, w2, b2, G, ws);

    dim3 grid(WW / TSX, HH / TSY, BB);
    refine_kernel<<<grid, dim3(256, 1, 1), 0, stream>>>(v0, G, ws, (float*)d_out);
}